// Round 4
// baseline (676.991 us; speedup 1.0000x reference)
//
#include <hip/hip_runtime.h>
#include <hip/hip_bf16.h>

#define MEM    150
#define GP     160
#define KX     300
#define KXP    320
#define KH     160
#define NLEAF  65536
#define NINT   21845
#define NTOT   87381
#define DEPTH  9

static const int SIZES[DEPTH] = {65536,16384,4096,1024,256,64,16,4,1};
static const int OFF[DEPTH]   = {0,65536,81920,86016,87040,87296,87360,87376,87380};

typedef __attribute__((ext_vector_type(8))) short short8;
typedef __attribute__((ext_vector_type(4))) float f32x4;
typedef unsigned short u16;

__device__ __forceinline__ float sigf(float x) { return 1.0f / (1.0f + __expf(-x)); }
__device__ __forceinline__ float tanhf_fast(float x) {
    float e = __expf(2.0f * x);
    return 1.0f - 2.0f / (e + 1.0f);
}
__device__ __forceinline__ u16 f2bf(float f) {
    union { float f; unsigned u; } v; v.f = f;
    unsigned r = v.u + 0x7FFF + ((v.u >> 16) & 1);
    return (u16)(r >> 16);
}
__device__ __forceinline__ float bf2f(u16 u) {
    union { unsigned u; float f; } v; v.u = ((unsigned)u) << 16; return v.f;
}
__device__ __forceinline__ unsigned pk2(float a, float b) {
    return (unsigned)f2bf(a) | ((unsigned)f2bf(b) << 16);
}
__device__ __forceinline__ void gl2lds16(const u16* g, u16* l) {
    __builtin_amdgcn_global_load_lds(
        (const __attribute__((address_space(1))) unsigned int*)g,
        (__attribute__((address_space(3))) unsigned int*)l,
        16, 0, 0);
}

// ---------------- prep: all weight packing + embs fp32->bf16 -------------------
// Gate-interleaved layouts (leaf + iuo-h): row c (0..479): t=c>>5, g=t%3
// (0=i,1=u,2=o), m=(t/3)*32+(c&31).
__global__ void prep(const float* __restrict__ E,
                     const float* __restrict__ Wix, const float* __restrict__ Wfx,
                     const float* __restrict__ Wux, const float* __restrict__ Wox,
                     const float* __restrict__ bix, const float* __restrict__ bfx,
                     const float* __restrict__ bux, const float* __restrict__ box,
                     const float* __restrict__ Wih, const float* __restrict__ Wfh,
                     const float* __restrict__ Wuh, const float* __restrict__ Woh,
                     const float* __restrict__ bfh,
                     const float* __restrict__ bih, const float* __restrict__ buh,
                     const float* __restrict__ boh,
                     u16* __restrict__ Abf,
                     u16* __restrict__ W4xT, float* __restrict__ b4x,
                     u16* __restrict__ WfhT, float* __restrict__ bfhp,
                     u16* __restrict__ WLeafT, float* __restrict__ bleaf,
                     u16* __restrict__ WiuoT, float* __restrict__ biuo)
{
    int stride = gridDim.x * blockDim.x;
    int tid = blockIdx.x * blockDim.x + threadIdx.x;
    // embs convert, K 300 -> 320 padded
    for (int i8 = tid; i8 < NTOT * (KXP / 8); i8 += stride) {
        int r = i8 / (KXP / 8), c8 = (i8 - r * (KXP / 8)) * 8;
        u16 v[8];
        if (c8 + 8 <= KX) {
            const float4* p = (const float4*)(E + (size_t)r * KX + c8);
            float4 f0 = p[0], f1 = p[1];
            v[0] = f2bf(f0.x); v[1] = f2bf(f0.y); v[2] = f2bf(f0.z); v[3] = f2bf(f0.w);
            v[4] = f2bf(f1.x); v[5] = f2bf(f1.y); v[6] = f2bf(f1.z); v[7] = f2bf(f1.w);
        } else {
            #pragma unroll
            for (int j = 0; j < 8; ++j) {
                int c = c8 + j;
                v[j] = (c < KX) ? f2bf(E[(size_t)r * KX + c]) : (u16)0;
            }
        }
        *(short8*)(Abf + (size_t)r * KXP + c8) = *(short8*)v;
    }
    // internal x-proj weights 640x320 [i|f|u|o]
    for (int idx = tid; idx < 640 * KXP; idx += stride) {
        int c = idx / KXP, k = idx - c * KXP;
        int g = c / GP, j = c - g * GP;
        const float* W = (g == 0) ? Wix : (g == 1) ? Wfx : (g == 2) ? Wux : Wox;
        W4xT[idx] = (j < MEM && k < KX) ? f2bf(W[k * MEM + j]) : (u16)0;
    }
    for (int idx = tid; idx < 640; idx += stride) {
        int g = idx / GP, j = idx - g * GP;
        const float* b = (g == 0) ? bix : (g == 1) ? bfx : (g == 2) ? bux : box;
        b4x[idx] = (j < MEM) ? b[j] : 0.0f;
    }
    // f-gate recurrent weights 256x160
    for (int idx = tid; idx < 256 * KH; idx += stride) {
        int c = idx / KH, k = idx - c * KH;
        WfhT[idx] = (c < MEM && k < MEM) ? f2bf(Wfh[k * MEM + c]) : (u16)0;
    }
    for (int idx = tid; idx < 256; idx += stride)
        bfhp[idx] = (idx < MEM) ? bfh[idx] : 0.0f;
    // leaf x-proj weights, gate-interleaved 480x320
    for (int idx = tid; idx < 480 * KXP; idx += stride) {
        int c = idx / KXP, k = idx - c * KXP;
        int tt = c >> 5, g = tt % 3, m = (tt / 3) * 32 + (c & 31);
        const float* W = (g == 0) ? Wix : (g == 1) ? Wux : Wox;
        WLeafT[idx] = (m < MEM && k < KX) ? f2bf(W[k * MEM + m]) : (u16)0;
    }
    for (int idx = tid; idx < 480; idx += stride) {
        int tt = idx >> 5, g = tt % 3, m = (tt / 3) * 32 + (idx & 31);
        float v = 0.0f;
        if (m < MEM) {
            const float* bx = (g == 0) ? bix : (g == 1) ? bux : box;
            const float* bh = (g == 0) ? bih : (g == 1) ? buh : boh;
            v = bx[m] + bh[m];
        }
        bleaf[idx] = v;
    }
    // iuo recurrent weights, gate-interleaved 480x160
    for (int idx = tid; idx < 480 * KH; idx += stride) {
        int c = idx / KH, k = idx - c * KH;
        int tt = c >> 5, g = tt % 3, m = (tt / 3) * 32 + (c & 31);
        const float* W = (g == 0) ? Wih : (g == 1) ? Wuh : Woh;
        WiuoT[idx] = (m < MEM && k < MEM) ? f2bf(W[k * MEM + m]) : (u16)0;
    }
    for (int idx = tid; idx < 480; idx += stride) {
        int tt = idx >> 5, g = tt % 3, m = (tt / 3) * 32 + (idx & 31);
        float v = 0.0f;
        if (m < MEM) {
            const float* bh = (g == 0) ? bih : (g == 1) ? buh : boh;
            v = bh[m];
        }
        biuo[idx] = v;
    }
}

// ---------------- plain MFMA GEMM (m97-style), bf16 out + bias -----------------
__global__ __launch_bounds__(256) void gemm_glds(
    const u16* __restrict__ A, int M, int K,
    const u16* __restrict__ BT, const float* __restrict__ bias,
    u16* __restrict__ Cout, int CP, int Ncols,
    int rowTiles, int colTiles)
{
    __shared__ __align__(16) u16 As[128 * 32];
    __shared__ __align__(16) u16 Bs[128 * 32];
    int bid = blockIdx.x;
    int grp = bid / (8 * colTiles);
    int rem = bid - grp * 8 * colTiles;
    int xt = grp * 8 + (rem & 7);
    int ct = rem >> 3;
    if (xt >= rowTiles) return;
    const int m0 = xt * 128, n0 = ct * 128;
    const int t = threadIdx.x;
    const int w = t >> 6, l = t & 63;
    const int l15 = l & 15, q = l >> 4;
    const int wm = (w & 1) * 64, wn = (w >> 1) * 64;

    const int srow0 = w * 32 + (l >> 2);
    const int srow1 = srow0 + 16;
    const int skk = (l & 3) * 8;
    int ar0 = m0 + srow0; if (ar0 >= M) ar0 = M - 1;
    int ar1 = m0 + srow1; if (ar1 >= M) ar1 = M - 1;
    const u16* Ab0 = A + (size_t)ar0 * K + skk;
    const u16* Ab1 = A + (size_t)ar1 * K + skk;
    const u16* Bb0 = BT + (size_t)(n0 + srow0) * K + skk;
    const u16* Bb1 = BT + (size_t)(n0 + srow1) * K + skk;
    u16* Asd0 = As + (w * 2) * 512;
    u16* Asd1 = As + (w * 2 + 1) * 512;
    u16* Bsd0 = Bs + (w * 2) * 512;
    u16* Bsd1 = Bs + (w * 2 + 1) * 512;

    f32x4 acc[4][4];
    #pragma unroll
    for (int i = 0; i < 4; ++i)
        #pragma unroll
        for (int j = 0; j < 4; ++j)
            acc[i][j] = (f32x4){0.f, 0.f, 0.f, 0.f};

    const int kiters = K >> 5;
    for (int kt = 0; kt < kiters; ++kt) {
        const int k0 = kt << 5;
        gl2lds16(Ab0 + k0, Asd0);
        gl2lds16(Ab1 + k0, Asd1);
        gl2lds16(Bb0 + k0, Bsd0);
        gl2lds16(Bb1 + k0, Bsd1);
        __syncthreads();
        short8 a[4], b[4];
        #pragma unroll
        for (int i = 0; i < 4; ++i)
            a[i] = *(const short8*)&As[(wm + i * 16 + l15) * 32 + q * 8];
        #pragma unroll
        for (int j = 0; j < 4; ++j)
            b[j] = *(const short8*)&Bs[(wn + j * 16 + l15) * 32 + q * 8];
        #pragma unroll
        for (int i = 0; i < 4; ++i)
            #pragma unroll
            for (int j = 0; j < 4; ++j)
                acc[i][j] = __builtin_amdgcn_mfma_f32_16x16x32_bf16(a[i], b[j], acc[i][j], 0, 0, 0);
        __syncthreads();
    }

    float bj[4];
    #pragma unroll
    for (int j = 0; j < 4; ++j) bj[j] = bias[n0 + wn + j * 16 + l15];
    #pragma unroll
    for (int i = 0; i < 4; ++i) {
        #pragma unroll
        for (int r = 0; r < 4; ++r) {
            int grow = m0 + wm + i * 16 + q * 4 + r;
            if (grow < M) {
                u16* crow = Cout + (size_t)grow * CP;
                #pragma unroll
                for (int j = 0; j < 4; ++j) {
                    int col = n0 + wn + j * 16 + l15;
                    if (col < Ncols) crow[col] = f2bf(acc[i][j][r] + bj[j]);
                }
            }
        }
    }
}

// ---------------- leaf x-proj GEMM fused with elementwise ----------------------
// Tile: 128 rows x 96 cols (32 m-values x 3 gates, gate-interleaved B).
// Waves 2x2: wm in {0,64}, wn in {0,48}. Epilogue -> Ep LDS -> c,h -> out/C/Hbf.
__global__ __launch_bounds__(256) void leaf_fused(
    const u16* __restrict__ A,      // Abf, 65536 x 320
    const u16* __restrict__ BT,     // WLeafT 480 x 320
    const float* __restrict__ bl,   // bleaf 480
    float* __restrict__ out, float* __restrict__ C, u16* __restrict__ Hbf)
{
    __shared__ __align__(16) u16 As[128 * 32];
    __shared__ __align__(16) u16 Bs[96 * 32];
    __shared__ float Ep[128 * 97];
    int bid = blockIdx.x;
    int grp = bid / 40;               // 8 xcd-slots * 5 col-tiles
    int rem = bid - grp * 40;
    int xt = grp * 8 + (rem & 7);     // 0..511
    int ct = rem >> 3;                // 0..4
    const int m0 = xt * 128;
    const int t = threadIdx.x, w = t >> 6, l = t & 63;
    const int l15 = l & 15, q = l >> 4;
    const int wm = (w & 1) * 64, wn = (w >> 1) * 48;
    const int crow = l >> 2, ckk = (l & 3) * 8;

    f32x4 acc[4][3];
    #pragma unroll
    for (int i = 0; i < 4; ++i)
        #pragma unroll
        for (int j = 0; j < 3; ++j)
            acc[i][j] = (f32x4){0.f, 0.f, 0.f, 0.f};

    for (int kt = 0; kt < KXP / 32; ++kt) {
        const int k0 = kt << 5;
        int c0 = 2 * w, c1 = 2 * w + 1;
        gl2lds16(A + (size_t)(m0 + c0 * 16 + crow) * KXP + k0 + ckk, As + c0 * 512);
        gl2lds16(A + (size_t)(m0 + c1 * 16 + crow) * KXP + k0 + ckk, As + c1 * 512);
        gl2lds16(BT + (size_t)(ct * 96 + w * 16 + crow) * KXP + k0 + ckk, Bs + w * 512);
        if (w < 2)
            gl2lds16(BT + (size_t)(ct * 96 + (4 + w) * 16 + crow) * KXP + k0 + ckk, Bs + (4 + w) * 512);
        __syncthreads();
        short8 a[4], b[3];
        #pragma unroll
        for (int i = 0; i < 4; ++i)
            a[i] = *(const short8*)&As[(wm + i * 16 + l15) * 32 + q * 8];
        #pragma unroll
        for (int j = 0; j < 3; ++j)
            b[j] = *(const short8*)&Bs[(wn + j * 16 + l15) * 32 + q * 8];
        #pragma unroll
        for (int i = 0; i < 4; ++i)
            #pragma unroll
            for (int j = 0; j < 3; ++j)
                acc[i][j] = __builtin_amdgcn_mfma_f32_16x16x32_bf16(a[i], b[j], acc[i][j], 0, 0, 0);
        __syncthreads();
    }

    #pragma unroll
    for (int i = 0; i < 4; ++i)
        #pragma unroll
        for (int j = 0; j < 3; ++j)
            #pragma unroll
            for (int r = 0; r < 4; ++r)
                Ep[(wm + i * 16 + q * 4 + r) * 97 + wn + j * 16 + l15] = acc[i][j][r];
    __syncthreads();

    for (int e = t; e < 128 * 32; e += 256) {
        int r = e >> 5, ml = e & 31;
        int m = ct * 32 + ml;
        int node = m0 + r;
        if (m < MEM) {
            float ip = Ep[r * 97 + ml]      + bl[ct * 96 + ml];
            float up = Ep[r * 97 + 32 + ml] + bl[ct * 96 + 32 + ml];
            float op = Ep[r * 97 + 64 + ml] + bl[ct * 96 + 64 + ml];
            float c = sigf(ip) * tanhf_fast(up);
            float h = sigf(op) * tanhf_fast(c);
            out[(size_t)node * MEM + m] = h;
            C[(size_t)node * MEM + m] = c;
            Hbf[(size_t)node * KH + m] = f2bf(h);
        } else {
            Hbf[(size_t)node * KH + m] = 0;
        }
    }
}

// ---------------- fused level kernel: hsum + iuo GEMM + elementwise ------------
// Block: 64 parents. Phase 0: hsum of 4 fp32 child h rows -> LDS bf16 A-tile.
// Phase 1: loop 5 gate-interleaved 96-col tiles x (K=160) MFMA; per-tile
// epilogue computes full gate math incl. f*c over children.
__global__ __launch_bounds__(256) void level_fused(
    const float* __restrict__ Hc,    // children h fp32, pitch 150
    const u16* __restrict__ BT,      // WiuoT 480 x 160
    const float* __restrict__ bl,    // biuo 480
    const u16* __restrict__ Pint,    // level x-preacts pitch 640 [i|f|u|o]
    const u16* __restrict__ Gf,      // children f preacts pitch 160
    const float* __restrict__ Cprev, // children c fp32, pitch 150
    float* __restrict__ outL, float* __restrict__ CL, u16* __restrict__ HbfL,
    int n)
{
    __shared__ __align__(16) u16 hs[64 * KH];
    __shared__ __align__(16) u16 Bs[96 * 32];
    __shared__ float Ep[64 * 97];
    const int p0 = blockIdx.x * 64;
    const int t = threadIdx.x, w = t >> 6, l = t & 63;
    const int l15 = l & 15, q = l >> 4;
    const int wm = (w & 1) * 32, wn = (w >> 1) * 48;
    const int crow = l >> 2, ckk = (l & 3) * 8;

    // phase 0: hsum (fp32 children h -> bf16 LDS, k padded to 160 with zeros)
    for (int idx = t; idx < 64 * 80; idx += 256) {
        int pl = idx / 80, k2 = idx - pl * 80;
        int par = p0 + pl;
        float s0 = 0.f, s1 = 0.f;
        if (par < n && k2 * 2 < MEM) {
            #pragma unroll
            for (int j = 0; j < 4; ++j) {
                float2 v = *(const float2*)(Hc + (size_t)(4 * par + j) * MEM + k2 * 2);
                s0 += v.x; s1 += v.y;
            }
        }
        *(unsigned*)&hs[pl * KH + k2 * 2] = pk2(s0, s1);
    }
    __syncthreads();

    for (int ct = 0; ct < 5; ++ct) {
        f32x4 acc[2][3];
        #pragma unroll
        for (int i = 0; i < 2; ++i)
            #pragma unroll
            for (int j = 0; j < 3; ++j)
                acc[i][j] = (f32x4){0.f, 0.f, 0.f, 0.f};
        for (int kt = 0; kt < KH / 32; ++kt) {
            const int k0 = kt << 5;
            gl2lds16(BT + (size_t)(ct * 96 + w * 16 + crow) * KH + k0 + ckk, Bs + w * 512);
            if (w < 2)
                gl2lds16(BT + (size_t)(ct * 96 + (4 + w) * 16 + crow) * KH + k0 + ckk, Bs + (4 + w) * 512);
            __syncthreads();
            short8 a[2], b[3];
            #pragma unroll
            for (int i = 0; i < 2; ++i)
                a[i] = *(const short8*)&hs[(wm + i * 16 + l15) * KH + k0 + q * 8];
            #pragma unroll
            for (int j = 0; j < 3; ++j)
                b[j] = *(const short8*)&Bs[(wn + j * 16 + l15) * 32 + q * 8];
            #pragma unroll
            for (int i = 0; i < 2; ++i)
                #pragma unroll
                for (int j = 0; j < 3; ++j)
                    acc[i][j] = __builtin_amdgcn_mfma_f32_16x16x32_bf16(a[i], b[j], acc[i][j], 0, 0, 0);
            __syncthreads();
        }
        #pragma unroll
        for (int i = 0; i < 2; ++i)
            #pragma unroll
            for (int j = 0; j < 3; ++j)
                #pragma unroll
                for (int r = 0; r < 4; ++r)
                    Ep[(wm + i * 16 + q * 4 + r) * 97 + wn + j * 16 + l15] = acc[i][j][r];
        __syncthreads();

        for (int e = t; e < 64 * 32; e += 256) {
            int r = e >> 5, ml = e & 31;
            int m = ct * 32 + ml;
            int par = p0 + r;
            if (par < n) {
                if (m < MEM) {
                    const u16* xr = Pint + (size_t)par * 640;
                    float ip = Ep[r * 97 + ml]      + bl[ct * 96 + ml]      + bf2f(xr[m]);
                    float fx = bf2f(xr[GP + m]);
                    float up = Ep[r * 97 + 32 + ml] + bl[ct * 96 + 32 + ml] + bf2f(xr[2 * GP + m]);
                    float op = Ep[r * 97 + 64 + ml] + bl[ct * 96 + 64 + ml] + bf2f(xr[3 * GP + m]);
                    float fc = 0.f;
                    #pragma unroll
                    for (int j = 0; j < 4; ++j) {
                        int ch = 4 * par + j;
                        fc += sigf(fx + bf2f(Gf[(size_t)ch * KH + m])) * Cprev[(size_t)ch * MEM + m];
                    }
                    float c = sigf(ip) * tanhf_fast(up) + fc;
                    float h = sigf(op) * tanhf_fast(c);
                    outL[(size_t)par * MEM + m] = h;
                    CL[(size_t)par * MEM + m] = c;
                    HbfL[(size_t)par * KH + m] = f2bf(h);
                } else {
                    HbfL[(size_t)par * KH + m] = 0;
                }
            }
        }
        __syncthreads();
    }
}

extern "C" void kernel_launch(void* const* d_in, const int* in_sizes, int n_in,
                              void* d_out, int out_size, void* d_ws, size_t ws_size,
                              hipStream_t stream)
{
    (void)in_sizes; (void)n_in; (void)out_size;
    const float* embs = (const float*)d_in[0];
    const float* Wix = (const float*)d_in[1];  const float* bix = (const float*)d_in[2];
    const float* Wfx = (const float*)d_in[3];  const float* bfx = (const float*)d_in[4];
    const float* Wux = (const float*)d_in[5];  const float* bux = (const float*)d_in[6];
    const float* Wox = (const float*)d_in[7];  const float* box = (const float*)d_in[8];
    const float* Wih = (const float*)d_in[9];  const float* bih = (const float*)d_in[10];
    const float* Wfh = (const float*)d_in[11]; const float* bfh = (const float*)d_in[12];
    const float* Wuh = (const float*)d_in[13]; const float* buh = (const float*)d_in[14];
    const float* Woh = (const float*)d_in[15]; const float* boh = (const float*)d_in[16];
    float* out = (float*)d_out;

    char* p = (char*)d_ws;
    auto alloc = [&](size_t bytes) -> char* {
        char* r = p;
        p += (bytes + 255) & ~(size_t)255;
        return r;
    };
    u16*   Abf    = (u16*)alloc((size_t)NTOT * KXP * 2);    // 55.9 MB
    u16*   PGint  = (u16*)alloc((size_t)NINT * 640 * 2);    // 28.0 MB
    u16*   Hbf    = (u16*)alloc((size_t)NTOT * KH * 2);     // 28.0 MB
    float* C      = (float*)alloc((size_t)NTOT * MEM * 4);  // 52.4 MB
    u16*   Gf     = (u16*)alloc((size_t)NLEAF * KH * 2);    // 21.0 MB
    u16*   W4xT   = (u16*)alloc((size_t)640 * KXP * 2);
    u16*   WfhT   = (u16*)alloc((size_t)256 * KH * 2);
    u16*   WLeafT = (u16*)alloc((size_t)480 * KXP * 2);
    u16*   WiuoT  = (u16*)alloc((size_t)480 * KH * 2);
    float* b4x    = (float*)alloc(640 * 4);
    float* bfhp   = (float*)alloc(256 * 4);
    float* bleaf  = (float*)alloc(480 * 4);
    float* biuo   = (float*)alloc(480 * 4);
    if ((size_t)(p - (char*)d_ws) > ws_size) return;

    prep<<<2048, 256, 0, stream>>>(embs, Wix, Wfx, Wux, Wox, bix, bfx, bux, box,
                                   Wih, Wfh, Wuh, Woh, bfh, bih, buh, boh,
                                   Abf, W4xT, b4x, WfhT, bfhp,
                                   WLeafT, bleaf, WiuoT, biuo);

    // leaf x-proj fused with leaf elementwise: 512 row-tiles x 5 col-tiles
    leaf_fused<<<2560, 256, 0, stream>>>(Abf, WLeafT, bleaf, out, C, Hbf);

    // internal x-proj -> PGint (pitch 640, + b_x)
    gemm_glds<<<((171 + 7) / 8) * 8 * 5, 256, 0, stream>>>(
        Abf + (size_t)NLEAF * KXP, NINT, KXP, W4xT, b4x, PGint, 640, 640, 171, 5);

    for (int d = 1; d < DEPTH; ++d) {
        int n = SIZES[d], np = SIZES[d - 1];
        int offp = OFF[d - 1], off = OFF[d];
        int rtf = (np + 127) / 128;
        // per-child f preacts: Gf = Hbf_children @ WfhT + bfh
        gemm_glds<<<((rtf + 7) / 8) * 8 * 2, 256, 0, stream>>>(
            Hbf + (size_t)offp * KH, np, KH, WfhT, bfhp, Gf, KH, KH, rtf, 2);
        // fused hsum + iuo GEMM + elementwise
        level_fused<<<(n + 63) / 64, 256, 0, stream>>>(
            out + (size_t)offp * MEM, WiuoT, biuo,
            PGint + (size_t)(off - NLEAF) * 640, Gf,
            C + (size_t)offp * MEM,
            out + (size_t)off * MEM, C + (size_t)off * MEM,
            Hbf + (size_t)off * KH, n);
    }
}

// Round 5
// 589.300 us; speedup vs baseline: 1.1488x; 1.1488x over previous
//
#include <hip/hip_runtime.h>
#include <hip/hip_bf16.h>

#define MEM    150
#define KX     300
#define KXP    320
#define KH     160
#define NLEAF  65536
#define NINT   21845
#define NTOT   87381
#define DEPTH  9

static const int SIZES[DEPTH] = {65536,16384,4096,1024,256,64,16,4,1};
static const int OFF[DEPTH]   = {0,65536,81920,86016,87040,87296,87360,87376,87380};

typedef __attribute__((ext_vector_type(8))) short short8;
typedef __attribute__((ext_vector_type(4))) float f32x4;
typedef unsigned short u16;

__device__ __forceinline__ float sigf(float x) { return 1.0f / (1.0f + __expf(-x)); }
__device__ __forceinline__ float tanhf_fast(float x) {
    float e = __expf(2.0f * x);
    return 1.0f - 2.0f / (e + 1.0f);
}
__device__ __forceinline__ u16 f2bf(float f) {
    union { float f; unsigned u; } v; v.f = f;
    unsigned r = v.u + 0x7FFF + ((v.u >> 16) & 1);
    return (u16)(r >> 16);
}
__device__ __forceinline__ float bf2f(u16 u) {
    union { unsigned u; float f; } v; v.u = ((unsigned)u) << 16; return v.f;
}
__device__ __forceinline__ unsigned pk2(float a, float b) {
    return (unsigned)f2bf(a) | ((unsigned)f2bf(b) << 16);
}
__device__ __forceinline__ void gl2lds16(const u16* g, u16* l) {
    __builtin_amdgcn_global_load_lds(
        (const __attribute__((address_space(1))) unsigned int*)g,
        (__attribute__((address_space(3))) unsigned int*)l,
        16, 0, 0);
}

// ---------------- prep: embs fp32->bf16 + weight packs -------------------------
// Interleave-16 B layout: row c -> t=c>>4, gate g=t%3, m=(t/3)*16+(c&15).
__global__ void prep(const float* __restrict__ E,
                     const float* __restrict__ Wix, const float* __restrict__ Wfx,
                     const float* __restrict__ Wux, const float* __restrict__ Wox,
                     const float* __restrict__ bix, const float* __restrict__ bfx,
                     const float* __restrict__ bux, const float* __restrict__ box,
                     const float* __restrict__ Wih, const float* __restrict__ Wfh,
                     const float* __restrict__ Wuh, const float* __restrict__ Woh,
                     u16* __restrict__ Abf,
                     u16* __restrict__ W4xT, float* __restrict__ b4x,
                     u16* __restrict__ WfhT, u16* __restrict__ WLeafT,
                     u16* __restrict__ WiuoT)
{
    int stride = gridDim.x * blockDim.x;
    int tid = blockIdx.x * blockDim.x + threadIdx.x;
    // embs convert, 300 -> 320 padded
    for (int i8 = tid; i8 < NTOT * (KXP / 8); i8 += stride) {
        int r = i8 / (KXP / 8), c8 = (i8 - r * (KXP / 8)) * 8;
        u16 v[8];
        if (c8 + 8 <= KX) {
            const float4* p = (const float4*)(E + (size_t)r * KX + c8);
            float4 f0 = p[0], f1 = p[1];
            v[0] = f2bf(f0.x); v[1] = f2bf(f0.y); v[2] = f2bf(f0.z); v[3] = f2bf(f0.w);
            v[4] = f2bf(f1.x); v[5] = f2bf(f1.y); v[6] = f2bf(f1.z); v[7] = f2bf(f1.w);
        } else {
            #pragma unroll
            for (int j = 0; j < 8; ++j) {
                int c = c8 + j;
                v[j] = (c < KX) ? f2bf(E[(size_t)r * KX + c]) : (u16)0;
            }
        }
        *(short8*)(Abf + (size_t)r * KXP + c8) = *(short8*)v;
    }
    // internal x-proj weights 640x320, straight [i|f|u|o] pitch-160 cols
    for (int idx = tid; idx < 640 * KXP; idx += stride) {
        int c = idx / KXP, k = idx - c * KXP;
        int g = c / KH, j = c - g * KH;
        const float* W = (g == 0) ? Wix : (g == 1) ? Wfx : (g == 2) ? Wux : Wox;
        W4xT[idx] = (j < MEM && k < KX) ? f2bf(W[k * MEM + j]) : (u16)0;
    }
    for (int idx = tid; idx < 640; idx += stride) {
        int g = idx / KH, j = idx - g * KH;
        const float* b = (g == 0) ? bix : (g == 1) ? bfx : (g == 2) ? bux : box;
        b4x[idx] = (j < MEM) ? b[j] : 0.0f;
    }
    // f-gate recurrent 160x160 (out-col m, k)
    for (int idx = tid; idx < 160 * KH; idx += stride) {
        int c = idx / KH, k = idx - c * KH;
        WfhT[idx] = (c < MEM && k < MEM) ? f2bf(Wfh[k * MEM + c]) : (u16)0;
    }
    // leaf x-proj, interleave-16, 480x320
    for (int idx = tid; idx < 480 * KXP; idx += stride) {
        int c = idx / KXP, k = idx - c * KXP;
        int t = c >> 4, g = t % 3, m = (t / 3) * 16 + (c & 15);
        const float* W = (g == 0) ? Wix : (g == 1) ? Wux : Wox;
        WLeafT[idx] = (m < MEM && k < KX) ? f2bf(W[k * MEM + m]) : (u16)0;
    }
    // iuo recurrent, interleave-16, 480x160
    for (int idx = tid; idx < 480 * KH; idx += stride) {
        int c = idx / KH, k = idx - c * KH;
        int t = c >> 4, g = t % 3, m = (t / 3) * 16 + (c & 15);
        const float* W = (g == 0) ? Wih : (g == 1) ? Wuh : Woh;
        WiuoT[idx] = (m < MEM && k < MEM) ? f2bf(W[k * MEM + m]) : (u16)0;
    }
}

// ---------------- plain MFMA GEMM (m97-style) for internal x-proj --------------
__global__ __launch_bounds__(256) void gemm_glds(
    const u16* __restrict__ A, int M, int K,
    const u16* __restrict__ BT, const float* __restrict__ bias,
    u16* __restrict__ Cout, int CP, int Ncols,
    int rowTiles, int colTiles)
{
    __shared__ __align__(16) u16 As[128 * 32];
    __shared__ __align__(16) u16 Bs[128 * 32];
    int bid = blockIdx.x;
    int grp = bid / (8 * colTiles);
    int rem = bid - grp * 8 * colTiles;
    int xt = grp * 8 + (rem & 7);
    int ct = rem >> 3;
    if (xt >= rowTiles) return;
    const int m0 = xt * 128, n0 = ct * 128;
    const int t = threadIdx.x;
    const int w = t >> 6, l = t & 63;
    const int l15 = l & 15, q = l >> 4;
    const int wm = (w & 1) * 64, wn = (w >> 1) * 64;
    const int crow = l >> 2, ckk = (l & 3) * 8;

    int ar0 = m0 + 2 * w * 16 + crow;       if (ar0 >= M) ar0 = M - 1;
    int ar1 = m0 + (2 * w + 1) * 16 + crow; if (ar1 >= M) ar1 = M - 1;
    const u16* Ab0 = A + (size_t)ar0 * K + ckk;
    const u16* Ab1 = A + (size_t)ar1 * K + ckk;
    const u16* Bb0 = BT + (size_t)(n0 + 2 * w * 16 + crow) * K + ckk;
    const u16* Bb1 = BT + (size_t)(n0 + (2 * w + 1) * 16 + crow) * K + ckk;

    f32x4 acc[4][4];
    #pragma unroll
    for (int i = 0; i < 4; ++i)
        #pragma unroll
        for (int j = 0; j < 4; ++j)
            acc[i][j] = (f32x4){0.f, 0.f, 0.f, 0.f};

    for (int kt = 0; kt < (K >> 5); ++kt) {
        const int k0 = kt << 5;
        gl2lds16(Ab0 + k0, As + (2 * w) * 512);
        gl2lds16(Ab1 + k0, As + (2 * w + 1) * 512);
        gl2lds16(Bb0 + k0, Bs + (2 * w) * 512);
        gl2lds16(Bb1 + k0, Bs + (2 * w + 1) * 512);
        __syncthreads();
        short8 a[4], b[4];
        #pragma unroll
        for (int i = 0; i < 4; ++i)
            a[i] = *(const short8*)&As[(wm + i * 16 + l15) * 32 + q * 8];
        #pragma unroll
        for (int j = 0; j < 4; ++j)
            b[j] = *(const short8*)&Bs[(wn + j * 16 + l15) * 32 + q * 8];
        #pragma unroll
        for (int i = 0; i < 4; ++i)
            #pragma unroll
            for (int j = 0; j < 4; ++j)
                acc[i][j] = __builtin_amdgcn_mfma_f32_16x16x32_bf16(a[i], b[j], acc[i][j], 0, 0, 0);
        __syncthreads();
    }

    float bj[4];
    #pragma unroll
    for (int j = 0; j < 4; ++j) bj[j] = bias[n0 + wn + j * 16 + l15];
    #pragma unroll
    for (int i = 0; i < 4; ++i)
        #pragma unroll
        for (int r = 0; r < 4; ++r) {
            int grow = m0 + wm + i * 16 + q * 4 + r;
            if (grow < M) {
                u16* crow2 = Cout + (size_t)grow * CP;
                #pragma unroll
                for (int j = 0; j < 4; ++j) {
                    int col = n0 + wn + j * 16 + l15;
                    if (col < Ncols) crow2[col] = f2bf(acc[i][j][r] + bj[j]);
                }
            }
        }
}

// ---------------- leaf: x-proj (i,u,o interleave-16) + in-register cell --------
// Blocks: (512 row-tiles x 5 col-chunks), XCD-swizzled. Tile 128 x 96.
__global__ __launch_bounds__(256) void leaf_k(
    const u16* __restrict__ A, const u16* __restrict__ BT,
    const float* __restrict__ bix, const float* __restrict__ bih,
    const float* __restrict__ bux, const float* __restrict__ buh,
    const float* __restrict__ box, const float* __restrict__ boh,
    float* __restrict__ out, float* __restrict__ C, u16* __restrict__ Hbf)
{
    __shared__ __align__(16) u16 As[128 * 32];
    __shared__ __align__(16) u16 Bs[96 * 32];
    int bid = blockIdx.x;
    int grp = bid / 40, rem = bid - grp * 40;
    int xt = grp * 8 + (rem & 7);
    int ct = rem >> 3;
    const int m0 = xt * 128;
    const int t = threadIdx.x, w = t >> 6, l = t & 63;
    const int l15 = l & 15, q = l >> 4;
    const int wm = (w & 1) * 64, wn = (w >> 1) * 48, wnIdx = w >> 1;
    const int crow = l >> 2, ckk = (l & 3) * 8;

    f32x4 acc[4][3];
    #pragma unroll
    for (int i = 0; i < 4; ++i)
        #pragma unroll
        for (int j = 0; j < 3; ++j)
            acc[i][j] = (f32x4){0.f, 0.f, 0.f, 0.f};

    for (int kt = 0; kt < KXP / 32; ++kt) {
        const int k0 = kt << 5;
        gl2lds16(A + (size_t)(m0 + 2 * w * 16 + crow) * KXP + k0 + ckk, As + (2 * w) * 512);
        gl2lds16(A + (size_t)(m0 + (2 * w + 1) * 16 + crow) * KXP + k0 + ckk, As + (2 * w + 1) * 512);
        gl2lds16(BT + (size_t)(ct * 96 + w * 16 + crow) * KXP + k0 + ckk, Bs + w * 512);
        if (w < 2)
            gl2lds16(BT + (size_t)(ct * 96 + (4 + w) * 16 + crow) * KXP + k0 + ckk, Bs + (4 + w) * 512);
        __syncthreads();
        short8 a[4], b[3];
        #pragma unroll
        for (int i = 0; i < 4; ++i)
            a[i] = *(const short8*)&As[(wm + i * 16 + l15) * 32 + q * 8];
        #pragma unroll
        for (int j = 0; j < 3; ++j)
            b[j] = *(const short8*)&Bs[(wn + j * 16 + l15) * 32 + q * 8];
        #pragma unroll
        for (int i = 0; i < 4; ++i)
            #pragma unroll
            for (int j = 0; j < 3; ++j)
                acc[i][j] = __builtin_amdgcn_mfma_f32_16x16x32_bf16(a[i], b[j], acc[i][j], 0, 0, 0);
        __syncthreads();
    }

    const int m = (ct * 2 + wnIdx) * 16 + l15;  // lane's output feature
    if (m < MEM) {
        float bi = bix[m] + bih[m], bu = bux[m] + buh[m], bo = box[m] + boh[m];
        #pragma unroll
        for (int i = 0; i < 4; ++i)
            #pragma unroll
            for (int r = 0; r < 4; ++r) {
                int node = m0 + wm + i * 16 + q * 4 + r;
                float c = sigf(acc[i][0][r] + bi) * tanhf_fast(acc[i][1][r] + bu);
                float h = sigf(acc[i][2][r] + bo) * tanhf_fast(c);
                out[(size_t)node * MEM + m] = h;
                C[(size_t)node * MEM + m] = c;
                Hbf[(size_t)node * KH + m] = f2bf(h);
            }
    } else {
        #pragma unroll
        for (int i = 0; i < 4; ++i)
            #pragma unroll
            for (int r = 0; r < 4; ++r)
                Hbf[(size_t)(m0 + wm + i * 16 + q * 4 + r) * KH + m] = 0;
    }
}

// ---------------- level K1: children -> fc (f-gate fused) + Hsum ---------------
// Tile: 128 children x 160 cols. A (Hbf children) staged full-K in LDS.
__global__ __launch_bounds__(256) void level_k1(
    const u16* __restrict__ Hc, const float* __restrict__ Cc,
    const u16* __restrict__ Px,      // this level's x-preacts, pitch 640
    const u16* __restrict__ BT,      // WfhT 160x160
    const float* __restrict__ bfh,
    float* __restrict__ fc, u16* __restrict__ Hsum, int np)
{
    __shared__ __align__(16) u16 As[128 * 160];   // 5 segs of 128x32
    __shared__ __align__(16) u16 Bs[160 * 32];
    const int n = np >> 2;
    const int m0 = blockIdx.x * 128;
    const int t = threadIdx.x, w = t >> 6, l = t & 63;
    const int l15 = l & 15, q = l >> 4;
    const int wm = (w & 1) * 64, wn = (w >> 1) * 80;
    const int crow = l >> 2, ckk = (l & 3) * 8;

    #pragma unroll
    for (int seg = 0; seg < 5; ++seg) {
        int r0 = m0 + 2 * w * 16 + crow;       if (r0 >= np) r0 = np - 1;
        int r1 = m0 + (2 * w + 1) * 16 + crow; if (r1 >= np) r1 = np - 1;
        gl2lds16(Hc + (size_t)r0 * KH + seg * 32 + ckk, As + seg * 4096 + (2 * w) * 512);
        gl2lds16(Hc + (size_t)r1 * KH + seg * 32 + ckk, As + seg * 4096 + (2 * w + 1) * 512);
    }
    __syncthreads();

    // Hsum from staged A: thread -> (parent pl, 4 k's)
    {
        int pl = t >> 3, kq = (t & 7) * 4;
        int par = (m0 >> 2) + pl;
        if (par < n) {
            #pragma unroll
            for (int seg = 0; seg < 5; ++seg) {
                float s0 = 0.f, s1 = 0.f, s2 = 0.f, s3 = 0.f;
                #pragma unroll
                for (int r = 0; r < 4; ++r) {
                    uint2 v = *(const uint2*)&As[seg * 4096 + (4 * pl + r) * 32 + kq];
                    s0 += bf2f((u16)(v.x & 0xffff)); s1 += bf2f((u16)(v.x >> 16));
                    s2 += bf2f((u16)(v.y & 0xffff)); s3 += bf2f((u16)(v.y >> 16));
                }
                uint2 o; o.x = pk2(s0, s1); o.y = pk2(s2, s3);
                *(uint2*)&Hsum[(size_t)par * KH + seg * 32 + kq] = o;
            }
        }
    }

    f32x4 acc[4][5];
    #pragma unroll
    for (int i = 0; i < 4; ++i)
        #pragma unroll
        for (int j = 0; j < 5; ++j)
            acc[i][j] = (f32x4){0.f, 0.f, 0.f, 0.f};

    for (int kt = 0; kt < 5; ++kt) {
        const int k0 = kt << 5;
        gl2lds16(BT + (size_t)(w * 16 + crow) * KH + k0 + ckk, Bs + w * 512);
        gl2lds16(BT + (size_t)((4 + w) * 16 + crow) * KH + k0 + ckk, Bs + (4 + w) * 512);
        if (w < 2)
            gl2lds16(BT + (size_t)((8 + w) * 16 + crow) * KH + k0 + ckk, Bs + (8 + w) * 512);
        __syncthreads();
        short8 a[4], b[5];
        #pragma unroll
        for (int i = 0; i < 4; ++i)
            a[i] = *(const short8*)&As[kt * 4096 + (wm + i * 16 + l15) * 32 + q * 8];
        #pragma unroll
        for (int j = 0; j < 5; ++j)
            b[j] = *(const short8*)&Bs[(wn + j * 16 + l15) * 32 + q * 8];
        #pragma unroll
        for (int i = 0; i < 4; ++i)
            #pragma unroll
            for (int j = 0; j < 5; ++j)
                acc[i][j] = __builtin_amdgcn_mfma_f32_16x16x32_bf16(a[i], b[j], acc[i][j], 0, 0, 0);
        __syncthreads();
    }

    // fc epilogue: each (i,q) owns one parent exclusively
    #pragma unroll
    for (int j = 0; j < 5; ++j) {
        int col = wn + j * 16 + l15;
        if (col < MEM) {
            float bfv = bfh[col];
            #pragma unroll
            for (int i = 0; i < 4; ++i) {
                int par = (m0 >> 2) + (wm >> 2) + i * 4 + q;
                if (par < n) {
                    float fx = bf2f(Px[(size_t)par * 640 + KH + col]);
                    float s = 0.f;
                    #pragma unroll
                    for (int r = 0; r < 4; ++r) {
                        int ch = 4 * par + r;
                        s += sigf(fx + bfv + acc[i][j][r]) * Cc[(size_t)ch * MEM + col];
                    }
                    fc[(size_t)par * KH + col] = s;
                }
            }
        }
    }
}

// ---------------- level K2: Hsum @ W_iuo (interleave-16) + in-register cell ----
// Tile: 64 parents x 480 cols (5 chunks of 96). A staged full-K.
__global__ __launch_bounds__(256) void level_k2(
    const u16* __restrict__ Hs, const u16* __restrict__ BT,
    const u16* __restrict__ Px, const float* __restrict__ fc,
    const float* __restrict__ bih, const float* __restrict__ buh,
    const float* __restrict__ boh,
    float* __restrict__ outL, float* __restrict__ CL, u16* __restrict__ HbfL,
    int n)
{
    __shared__ __align__(16) u16 As[64 * 160];    // 5 segs of 64x32
    __shared__ __align__(16) u16 Bs[96 * 32];
    const int p0 = blockIdx.x * 64;
    const int t = threadIdx.x, w = t >> 6, l = t & 63;
    const int l15 = l & 15, q = l >> 4;
    const int wm = (w & 1) * 32, wn = (w >> 1) * 48, wnIdx = w >> 1;
    const int crow = l >> 2, ckk = (l & 3) * 8;

    #pragma unroll
    for (int seg = 0; seg < 5; ++seg) {
        int r0 = p0 + w * 16 + crow; if (r0 >= n) r0 = n - 1;
        gl2lds16(Hs + (size_t)r0 * KH + seg * 32 + ckk, As + seg * 2048 + w * 512);
    }

    for (int ct = 0; ct < 5; ++ct) {
        f32x4 acc[2][3];
        #pragma unroll
        for (int i = 0; i < 2; ++i)
            #pragma unroll
            for (int j = 0; j < 3; ++j)
                acc[i][j] = (f32x4){0.f, 0.f, 0.f, 0.f};
        for (int kt = 0; kt < 5; ++kt) {
            const int k0 = kt << 5;
            gl2lds16(BT + (size_t)(ct * 96 + w * 16 + crow) * KH + k0 + ckk, Bs + w * 512);
            if (w < 2)
                gl2lds16(BT + (size_t)(ct * 96 + (4 + w) * 16 + crow) * KH + k0 + ckk, Bs + (4 + w) * 512);
            __syncthreads();
            short8 a[2], b[3];
            #pragma unroll
            for (int i = 0; i < 2; ++i)
                a[i] = *(const short8*)&As[kt * 2048 + (wm + i * 16 + l15) * 32 + q * 8];
            #pragma unroll
            for (int j = 0; j < 3; ++j)
                b[j] = *(const short8*)&Bs[(wn + j * 16 + l15) * 32 + q * 8];
            #pragma unroll
            for (int i = 0; i < 2; ++i)
                #pragma unroll
                for (int j = 0; j < 3; ++j)
                    acc[i][j] = __builtin_amdgcn_mfma_f32_16x16x32_bf16(a[i], b[j], acc[i][j], 0, 0, 0);
            __syncthreads();
        }
        const int m = (ct * 2 + wnIdx) * 16 + l15;
        if (m < MEM) {
            float bi = bih[m], bu = buh[m], bo = boh[m];
            #pragma unroll
            for (int i = 0; i < 2; ++i)
                #pragma unroll
                for (int r = 0; r < 4; ++r) {
                    int par = p0 + wm + i * 16 + q * 4 + r;
                    if (par < n) {
                        const u16* xr = Px + (size_t)par * 640;
                        float ip = acc[i][0][r] + bf2f(xr[m]) + bi;
                        float up = acc[i][1][r] + bf2f(xr[2 * KH + m]) + bu;
                        float op = acc[i][2][r] + bf2f(xr[3 * KH + m]) + bo;
                        float c = sigf(ip) * tanhf_fast(up) + fc[(size_t)par * KH + m];
                        float h = sigf(op) * tanhf_fast(c);
                        outL[(size_t)par * MEM + m] = h;
                        CL[(size_t)par * MEM + m] = c;
                        HbfL[(size_t)par * KH + m] = f2bf(h);
                    }
                }
        } else {
            #pragma unroll
            for (int i = 0; i < 2; ++i)
                #pragma unroll
                for (int r = 0; r < 4; ++r) {
                    int par = p0 + wm + i * 16 + q * 4 + r;
                    if (par < n) HbfL[(size_t)par * KH + m] = 0;
                }
        }
    }
}

extern "C" void kernel_launch(void* const* d_in, const int* in_sizes, int n_in,
                              void* d_out, int out_size, void* d_ws, size_t ws_size,
                              hipStream_t stream)
{
    (void)in_sizes; (void)n_in; (void)out_size;
    const float* embs = (const float*)d_in[0];
    const float* Wix = (const float*)d_in[1];  const float* bix = (const float*)d_in[2];
    const float* Wfx = (const float*)d_in[3];  const float* bfx = (const float*)d_in[4];
    const float* Wux = (const float*)d_in[5];  const float* bux = (const float*)d_in[6];
    const float* Wox = (const float*)d_in[7];  const float* box = (const float*)d_in[8];
    const float* Wih = (const float*)d_in[9];  const float* bih = (const float*)d_in[10];
    const float* Wfh = (const float*)d_in[11]; const float* bfh = (const float*)d_in[12];
    const float* Wuh = (const float*)d_in[13]; const float* buh = (const float*)d_in[14];
    const float* Woh = (const float*)d_in[15]; const float* boh = (const float*)d_in[16];
    float* out = (float*)d_out;

    char* p = (char*)d_ws;
    auto alloc = [&](size_t bytes) -> char* {
        char* r = p;
        p += (bytes + 255) & ~(size_t)255;
        return r;
    };
    u16*   Abf    = (u16*)alloc((size_t)NTOT * KXP * 2);    // 55.9 MB
    u16*   PGint  = (u16*)alloc((size_t)NINT * 640 * 2);    // 28.0 MB
    u16*   Hbf    = (u16*)alloc((size_t)NTOT * KH * 2);     // 28.0 MB
    float* C      = (float*)alloc((size_t)NTOT * MEM * 4);  // 52.4 MB
    float* fcb    = (float*)alloc((size_t)16384 * KH * 4);  // 10.5 MB
    u16*   Hsum   = (u16*)alloc((size_t)16384 * KH * 2);    //  5.2 MB
    u16*   W4xT   = (u16*)alloc((size_t)640 * KXP * 2);
    u16*   WfhT   = (u16*)alloc((size_t)160 * KH * 2);
    u16*   WLeafT = (u16*)alloc((size_t)480 * KXP * 2);
    u16*   WiuoT  = (u16*)alloc((size_t)480 * KH * 2);
    float* b4x    = (float*)alloc(640 * 4);
    if ((size_t)(p - (char*)d_ws) > ws_size) return;

    prep<<<2048, 256, 0, stream>>>(embs, Wix, Wfx, Wux, Wox, bix, bfx, bux, box,
                                   Wih, Wfh, Wuh, Woh,
                                   Abf, W4xT, b4x, WfhT, WLeafT, WiuoT);

    // internal x-proj -> PGint (pitch 640, +b_x), straight layout
    gemm_glds<<<((171 + 7) / 8) * 8 * 5, 256, 0, stream>>>(
        Abf + (size_t)NLEAF * KXP, NINT, KXP, W4xT, b4x, PGint, 640, 640, 171, 5);

    // leaf x-proj + cell, fully fused, in-register epilogue
    leaf_k<<<512 / 8 * 8 * 5, 256, 0, stream>>>(
        Abf, WLeafT, bix, bih, bux, buh, box, boh, out, C, Hbf);

    for (int d = 1; d < DEPTH; ++d) {
        int n = SIZES[d], np = SIZES[d - 1];
        int offp = OFF[d - 1], off = OFF[d];
        level_k1<<<(np + 127) / 128, 256, 0, stream>>>(
            Hbf + (size_t)offp * KH, C + (size_t)offp * MEM,
            PGint + (size_t)(off - NLEAF) * 640, WfhT, bfh,
            fcb, Hsum, np);
        level_k2<<<(n + 63) / 64, 256, 0, stream>>>(
            Hsum, WiuoT, PGint + (size_t)(off - NLEAF) * 640, fcb,
            bih, buh, boh,
            out + (size_t)off * MEM, C + (size_t)off * MEM,
            Hbf + (size_t)off * KH, n);
    }
}